// Round 7
// baseline (312.066 us; speedup 1.0000x reference)
//
#include <hip/hip_runtime.h>
#include <hip/hip_bf16.h>
#include <cstdint>
#include <cmath>

#define B_ 4
#define T_ 2048
#define C_ 768
#define H_ 12
#define D_ 64
#define MLP_ 3072
#define BT_ (B_*T_)

typedef __hip_bfloat16 hbf;
typedef __bf16 bf16_t;
typedef bf16_t bf16x8 __attribute__((ext_vector_type(8)));
typedef bf16_t bf16x4 __attribute__((ext_vector_type(4)));
typedef float f32x4 __attribute__((ext_vector_type(4)));

static __device__ __forceinline__ void load_lds16(const void* g, void* l) {
    __builtin_amdgcn_global_load_lds(
        (const __attribute__((address_space(1))) unsigned int*)g,
        (__attribute__((address_space(3))) unsigned int*)l, 16, 0, 0);
}

// ---------------- LDS-tiled transpose: f32 [R][S] -> bf16 [S][R] ----------------
__global__ __launch_bounds__(256) void transpose_pack(
    const float* __restrict__ src, hbf* __restrict__ dst, int R, int S)
{
    __shared__ float tl[64 * 65];
    src += (size_t)blockIdx.z * R * S;
    dst += (size_t)blockIdx.z * R * S;
    const int r0 = blockIdx.y * 64, s0 = blockIdx.x * 64;
    const int c = threadIdx.x & 63, q = threadIdx.x >> 6;
#pragma unroll
    for (int j = 0; j < 16; ++j) {
        int r = q + j * 4;
        tl[r * 65 + c] = src[(size_t)(r0 + r) * S + s0 + c];
    }
    __syncthreads();
#pragma unroll
    for (int j = 0; j < 16; ++j) {
        int s = q + j * 4;
        dst[(size_t)(s0 + s) * R + r0 + c] = __float2bfloat16(tl[c * 65 + s]);
    }
}

// Combined q/k/v weight pack: 36 z-slices of [768][64] -> [64][768] bf16.
// z = mtx*12 + head; mtx 0,1 -> WqkT (q rows 0..767, k rows 768..1535); 2 -> WvT.
__global__ __launch_bounds__(256) void pack_qkv3(
    const float* __restrict__ Wq, const float* __restrict__ Wk,
    const float* __restrict__ Wv, hbf* __restrict__ WqkT, hbf* __restrict__ WvT)
{
    __shared__ float tl[64 * 65];
    const int z = blockIdx.z;
    const int mtx = z / 12, head = z - mtx * 12;
    const float* src = (mtx == 0 ? Wq : mtx == 1 ? Wk : Wv) + (size_t)head * 49152;
    hbf* dst = (mtx == 2) ? (WvT + (size_t)head * 49152)
                          : (WqkT + (size_t)(mtx * 12 + head) * 49152);
    const int r0 = blockIdx.y * 64;
    const int c = threadIdx.x & 63, q = threadIdx.x >> 6;
#pragma unroll
    for (int j = 0; j < 16; ++j) {
        int r = q + j * 4;
        tl[r * 65 + c] = src[(size_t)(r0 + r) * 64 + c];
    }
    __syncthreads();
#pragma unroll
    for (int j = 0; j < 16; ++j) {
        int s = q + j * 4;
        dst[(size_t)s * 768 + r0 + c] = __float2bfloat16(tl[c * 65 + s]);
    }
}

// ---------------- layernorm (row = 768) ----------------
__global__ __launch_bounds__(256) void ln_kernel(
    const float* __restrict__ x, const float* __restrict__ g,
    const float* __restrict__ bb, hbf* __restrict__ out)
{
    __shared__ float red[8];
    const int row = blockIdx.x;
    const float* xr = x + (size_t)row * C_;
    const int t = threadIdx.x;
    float v0 = xr[t], v1 = xr[t + 256], v2 = xr[t + 512];
    float s = v0 + v1 + v2;
    float s2 = v0 * v0 + v1 * v1 + v2 * v2;
#pragma unroll
    for (int m = 1; m < 64; m <<= 1) {
        s  += __shfl_xor(s,  m, 64);
        s2 += __shfl_xor(s2, m, 64);
    }
    if ((t & 63) == 0) { red[t >> 6] = s; red[4 + (t >> 6)] = s2; }
    __syncthreads();
    float S  = red[0] + red[1] + red[2] + red[3];
    float S2 = red[4] + red[5] + red[6] + red[7];
    float mu  = S * (1.0f / C_);
    float var = S2 * (1.0f / C_) - mu * mu;
    float inv = rsqrtf(var + 1e-6f);
    hbf* orow = out + (size_t)row * C_;
    orow[t]       = __float2bfloat16((v0 - mu) * inv * g[t]       + bb[t]);
    orow[t + 256] = __float2bfloat16((v1 - mu) * inv * g[t + 256] + bb[t + 256]);
    orow[t + 512] = __float2bfloat16((v2 - mu) * inv * g[t + 512] + bb[t + 512]);
}

// ---------------- GEMM: C[M,N] = A[M,K](bf16) * Bt[N,K](bf16)^T ----------------
// BK=64, 128x128 tile, XOR-swizzled LDS, SINGLE buffer (32 KB -> 3 blocks/CU),
// m97-style 2-barrier loop, 1D grid + XCD swizzle.
template<int EPI>
__global__ __launch_bounds__(256, 3) void gemm_kernel(
    const hbf* __restrict__ A, const hbf* __restrict__ Bt,
    float* __restrict__ outF, hbf* __restrict__ outH,
    const float* __restrict__ bias, const float* __restrict__ resid,
    int M, int N, int K,
    hbf* __restrict__ qb, hbf* __restrict__ kb,
    float scale, int gx)
{
    __shared__ hbf sA[128 * 64];
    __shared__ hbf sB[128 * 64];
    const int tid = threadIdx.x;
    const int lane = tid & 63;
    const int wid = tid >> 6;
    const int wm = wid >> 1, wn = wid & 1;
    const int lr = lane & 15, hg = lane >> 4;
    const int bid = blockIdx.x, nwg = gridDim.x;
    const int wg = (bid & 7) * (nwg >> 3) + (bid >> 3);
    const int bx = wg % gx, by = wg / gx;
    const int row0 = by * 128;
    const int col0 = bx * 128;

    f32x4 acc[4][4] = {};

    int offG[4];
    const int Kb = K * 2;
#pragma unroll
    for (int i = 0; i < 4; ++i) {
        int c = tid + i * 256;
        offG[i] = (c >> 3) * Kb + (((c & 7) ^ ((c >> 3) & 7)) << 4);
    }
    const char* gA = (const char*)(A + (size_t)row0 * K);
    const char* gB = (const char*)(Bt + (size_t)col0 * K);

    auto stage = [&](int kt) {
        const int kb2 = kt * 128;
#pragma unroll
        for (int i = 0; i < 4; ++i) {
            load_lds16(gA + (size_t)(offG[i] + kb2), (char*)sA + i * 4096 + wid * 1024);
            load_lds16(gB + (size_t)(offG[i] + kb2), (char*)sB + i * 4096 + wid * 1024);
        }
    };

    const int NK = K >> 6;
    stage(0);
    for (int kt = 0; kt < NK; ++kt) {
        __syncthreads();   // drains staged loads (compiler emits vmcnt(0) at barrier)
#pragma unroll
        for (int kf = 0; kf < 2; ++kf) {
            const int sl = ((kf * 4 + hg) ^ (lr & 7)) << 4;
            bf16x8 af[4], bfr[4];
#pragma unroll
            for (int m = 0; m < 4; ++m)
                af[m] = *(const bf16x8*)((const char*)sA + (wm * 64 + m * 16 + lr) * 128 + sl);
#pragma unroll
            for (int n = 0; n < 4; ++n)
                bfr[n] = *(const bf16x8*)((const char*)sB + (wn * 64 + n * 16 + lr) * 128 + sl);
#pragma unroll
            for (int m = 0; m < 4; ++m)
#pragma unroll
                for (int n = 0; n < 4; ++n)
                    acc[m][n] = __builtin_amdgcn_mfma_f32_16x16x32_bf16(af[m], bfr[n], acc[m][n], 0, 0, 0);
        }
        __syncthreads();   // all waves done reading before restage
        if (kt + 1 < NK) stage(kt + 1);
    }

#pragma unroll
    for (int m = 0; m < 4; ++m) {
#pragma unroll
        for (int n = 0; n < 4; ++n) {
#pragma unroll
            for (int j = 0; j < 4; ++j) {
                int row = row0 + wm * 64 + m * 16 + hg * 4 + j;
                int col = col0 + wn * 64 + n * 16 + lr;
                float v = acc[m][n][j];
                if constexpr (EPI == 0) {
                    outH[(size_t)row * N + col] = __float2bfloat16(v);
                } else if constexpr (EPI == 1) {
                    outF[(size_t)row * N + col] = v + bias[col] + resid[(size_t)row * N + col];
                } else if constexpr (EPI == 2) {
                    float tt = v + bias[col];
                    float ge = 0.5f * tt * (1.0f + erff(tt * 0.70710678118654752f));
                    outH[(size_t)row * N + col] = __float2bfloat16(ge);
                } else {
                    int typ = col / C_;            // 0=q, 1=k
                    int rr = col - typ * C_;
                    int h = rr >> 6, d = rr & 63;
                    int b = row >> 11, t = row & (T_ - 1);
                    size_t bh = (size_t)b * H_ + h;
                    if (typ == 0) qb[(bh * T_ + t) * D_ + d] = __float2bfloat16(v * scale);
                    else          kb[(bh * T_ + t) * D_ + d] = __float2bfloat16(v);
                }
            }
        }
    }
}

// ---------------- flash attention (swapped QK^T, defer-max, __expf) ------------
// 1D grid 1536 (XCD-swizzled). 4 waves x 16 q-rows = 64 q-rows/block.
// q pre-scaled by 768^-0.5. vT is [hd=768][B*T=8192]. LDS 40 KB -> 4 blocks/CU.
__global__ __launch_bounds__(256, 4) void attn_kernel(
    const hbf* __restrict__ qg, const hbf* __restrict__ kg,
    const hbf* __restrict__ vg, hbf* __restrict__ outA)
{
    __shared__ hbf sK0[64 * 64], sK1[64 * 64];   // [s][d], swizzled
    __shared__ hbf sV0[64 * 64], sV1[64 * 64];   // [d][s], swizzled
    __shared__ hbf sP[4 * 16 * 64];              // per wave [q=16][kv=64], swizzled
    const int tid = threadIdx.x, lane = tid & 63, wid = tid >> 6;
    const int lr = lane & 15, hg = lane >> 4;
    const int wg = (blockIdx.x & 7) * 192 + (blockIdx.x >> 3);   // 1536/8 = 192
    const int bh = wg >> 5;                        // 32 q-tiles per bh
    const int b = bh / H_, h = bh - b * H_;
    const int wr0 = (wg & 31) * 64 + wid * 16;
    const hbf* qbh = qg + (size_t)bh * T_ * D_;
    const hbf* kbh = kg + (size_t)bh * T_ * D_;
    const hbf* vbh = vg + (size_t)h * 64 * BT_ + (size_t)b * T_;

    bf16x8 a_q[2];
#pragma unroll
    for (int kf = 0; kf < 2; ++kf)
        a_q[kf] = *(const bf16x8*)(qbh + (size_t)(wr0 + lr) * D_ + kf * 32 + hg * 8);

    f32x4 o[4] = {};
    float mreg = -3e38f;
    float lrun = 0.0f;

    int offK[2], offV[2];
#pragma unroll
    for (int i = 0; i < 2; ++i) {
        int c = tid + i * 256;
        int sw = ((c & 7) ^ ((c >> 3) & 7)) << 4;
        offK[i] = (c >> 3) * 128 + sw;
        offV[i] = (c >> 3) * (BT_ * 2) + sw;
    }
    hbf* sPw = sP + wid * (16 * 64);
    const int sl0 = ((0 * 4 + hg) ^ (lr & 7)) << 4;
    const int sl1 = ((1 * 4 + hg) ^ (lr & 7)) << 4;
    const int bcast = hg * 20;   // source lane hg*16 + hg*4 (+j): lr == q-row hg*4+j

    auto stage = [&](int itn, hbf* sKd, hbf* sVd) {
        const char* kp = (const char*)kbh + (size_t)itn * 8192;
        const char* vp = (const char*)vbh + (size_t)itn * 128;
#pragma unroll
        for (int i = 0; i < 2; ++i) {
            load_lds16(kp + offK[i], (char*)sKd + i * 4096 + wid * 1024);
            load_lds16(vp + offV[i], (char*)sVd + i * 4096 + wid * 1024);
        }
    };

    auto tile = [&](const hbf* sKc, const hbf* sVc) {
        // swapped QK^T: st[n] has kv-row = n*16+hg*4+j, q-col = lr
        f32x4 st[4] = {};
        __builtin_amdgcn_s_setprio(1);
#pragma unroll
        for (int kf = 0; kf < 2; ++kf) {
            const int sl = kf ? sl1 : sl0;
#pragma unroll
            for (int n = 0; n < 4; ++n) {
                bf16x8 ak = *(const bf16x8*)((const char*)sKc + (n * 16 + lr) * 128 + sl);
                st[n] = __builtin_amdgcn_mfma_f32_16x16x32_bf16(ak, a_q[kf], st[n], 0, 0, 0);
            }
        }
        __builtin_amdgcn_s_setprio(0);

        float t = st[0][0];
#pragma unroll
        for (int n = 0; n < 4; ++n)
#pragma unroll
            for (int j = 0; j < 4; ++j)
                if (n + j > 0) t = fmaxf(t, st[n][j]);
        t = fmaxf(t, __shfl_xor(t, 16, 64));
        t = fmaxf(t, __shfl_xor(t, 32, 64));
        if (__any(t - mreg > 8.0f)) {       // defer-max: rarely taken
            float nm = fmaxf(mreg, t);
            float fac = __expf(mreg - nm);
            mreg = nm;
            lrun *= fac;
            float fb[4];
#pragma unroll
            for (int j = 0; j < 4; ++j)
                fb[j] = __shfl(fac, bcast + j, 64);
#pragma unroll
            for (int nd = 0; nd < 4; ++nd)
#pragma unroll
                for (int j = 0; j < 4; ++j)
                    o[nd][j] *= fb[j];
        }
        float ps = 0.0f;
#pragma unroll
        for (int n = 0; n < 4; ++n) {
            float p0 = __expf(st[n][0] - mreg);
            float p1 = __expf(st[n][1] - mreg);
            float p2 = __expf(st[n][2] - mreg);
            float p3 = __expf(st[n][3] - mreg);
            ps += (p0 + p1) + (p2 + p3);
            bf16x4 w;
            w[0] = (bf16_t)p0; w[1] = (bf16_t)p1; w[2] = (bf16_t)p2; w[3] = (bf16_t)p3;
            *(bf16x4*)((char*)sPw + lr * 128 +
                       (((n * 2 + (hg >> 1)) ^ (lr & 7)) << 4) + ((hg & 1) * 8)) = w;
        }
        ps += __shfl_xor(ps, 16, 64);
        ps += __shfl_xor(ps, 32, 64);
        lrun += ps;

        // PV: P is wave-private (in-order DS pipe; no block barrier needed)
        __builtin_amdgcn_s_setprio(1);
#pragma unroll
        for (int kf = 0; kf < 2; ++kf) {
            const int sl = kf ? sl1 : sl0;
            bf16x8 ap = *(const bf16x8*)((const char*)sPw + lr * 128 + sl);
#pragma unroll
            for (int nd = 0; nd < 4; ++nd) {
                bf16x8 bv = *(const bf16x8*)((const char*)sVc + (nd * 16 + lr) * 128 + sl);
                o[nd] = __builtin_amdgcn_mfma_f32_16x16x32_bf16(ap, bv, o[nd], 0, 0, 0);
            }
        }
        __builtin_amdgcn_s_setprio(0);
    };

    const int NT = T_ / 64;   // 32, even
    stage(0, sK0, sV0);
    __syncthreads();
    for (int it = 0; it < NT; it += 2) {
        stage(it + 1, sK1, sV1);            // it+1 < NT always
        tile(sK0, sV0);
        __syncthreads();
        if (it + 2 < NT) stage(it + 2, sK0, sV0);
        tile(sK1, sV1);
        __syncthreads();
    }

    float lb[4];
#pragma unroll
    for (int j = 0; j < 4; ++j)
        lb[j] = __shfl(lrun, bcast + j, 64);
#pragma unroll
    for (int nd = 0; nd < 4; ++nd)
#pragma unroll
        for (int j = 0; j < 4; ++j) {
            int row = wr0 + hg * 4 + j;
            int col = nd * 16 + lr;
            float val = o[nd][j] / lb[j];
            outA[((size_t)(b * T_ + row)) * C_ + h * D_ + col] = __float2bfloat16(val);
        }
}

// ---------------- launch ----------------
extern "C" void kernel_launch(void* const* d_in, const int* in_sizes, int n_in,
                              void* d_out, int out_size, void* d_ws, size_t ws_size,
                              hipStream_t stream)
{
    const float* x    = (const float*)d_in[0];
    const float* Wq   = (const float*)d_in[1];
    const float* Wk   = (const float*)d_in[2];
    const float* Wv   = (const float*)d_in[3];
    const float* Wo   = (const float*)d_in[4];
    const float* bo   = (const float*)d_in[5];
    const float* ln1g = (const float*)d_in[6];
    const float* ln1b = (const float*)d_in[7];
    const float* ln2g = (const float*)d_in[8];
    const float* ln2b = (const float*)d_in[9];
    const float* W1   = (const float*)d_in[10];
    const float* b1   = (const float*)d_in[11];
    const float* W2   = (const float*)d_in[12];
    const float* b2   = (const float*)d_in[13];
    float* out = (float*)d_out;
    char* ws = (char*)d_ws;

    hbf*  xn    = (hbf*)(ws + 0);            // 12.58 MB
    hbf*  WqkT  = (hbf*)(ws + 12582912);     // [1536][768] 2.36 MB
    hbf*  WvT   = (hbf*)(ws + 14942208);     // [768][768]  1.18 MB
    hbf*  qb    = (hbf*)(ws + 16121856);     // 12.58 MB
    hbf*  kb    = (hbf*)(ws + 28704768);     // 12.58 MB
    hbf*  vT    = (hbf*)(ws + 41287680);     // [768][8192] 12.58 MB
    hbf*  h1    = (hbf*)(ws + 0);            // 50.33 MB overlay (dead inputs by MLP)
    hbf*  attnB = (hbf*)(ws + 53870592);     // 12.58 MB
    hbf*  yln   = (hbf*)(ws + 53870592);     // overlays attnB
    float* x2   = (float*)(ws + 66453504);   // 25.17 MB
    hbf*  WoT   = (hbf*)(ws + 91619328);     // 1.18 MB
    hbf*  W1T   = (hbf*)(ws + 92798976);     // 4.72 MB
    hbf*  W2T   = (hbf*)(ws + 97517568);     // 4.72 MB (end 102,236,160)

    const float SCALE = 0.036084391824351615f;  // 768^-0.5

    pack_qkv3<<<dim3(1, 12, 36), 256, 0, stream>>>(Wq, Wk, Wv, WqkT, WvT);
    transpose_pack<<<dim3(12, 12, 1), 256, 0, stream>>>(Wo, WoT, 768, 768);
    transpose_pack<<<dim3(48, 12, 1), 256, 0, stream>>>(W1, W1T, 768, 3072);
    transpose_pack<<<dim3(12, 48, 1), 256, 0, stream>>>(W2, W2T, 3072, 768);
    ln_kernel<<<8192, 256, 0, stream>>>(x, ln1g, ln1b, xn);
    gemm_kernel<3><<<768, 256, 0, stream>>>(xn, WqkT, nullptr, nullptr, nullptr, nullptr,
        8192, 1536, 768, qb, kb, SCALE, 12);
    gemm_kernel<0><<<384, 256, 0, stream>>>(WvT, xn, nullptr, vT, nullptr, nullptr,
        768, BT_, 768, nullptr, nullptr, 1.0f, 64);
    attn_kernel<<<1536, 256, 0, stream>>>(qb, kb, vT, attnB);
    gemm_kernel<1><<<384, 256, 0, stream>>>(attnB, WoT, x2, nullptr, bo, x,
        8192, 768, 768, nullptr, nullptr, 1.0f, 6);
    ln_kernel<<<8192, 256, 0, stream>>>(x2, ln2g, ln2b, yln);
    gemm_kernel<2><<<1536, 256, 0, stream>>>(yln, W1T, nullptr, h1, b1, nullptr,
        8192, 3072, 768, nullptr, nullptr, 1.0f, 24);
    gemm_kernel<1><<<384, 256, 0, stream>>>(h1, W2T, out, nullptr, b2, x2,
        8192, 768, 3072, nullptr, nullptr, 1.0f, 6);
}

// Round 8
// 289.483 us; speedup vs baseline: 1.0780x; 1.0780x over previous
//
#include <hip/hip_runtime.h>
#include <hip/hip_bf16.h>
#include <cstdint>
#include <cmath>

#define B_ 4
#define T_ 2048
#define C_ 768
#define H_ 12
#define D_ 64
#define MLP_ 3072
#define BT_ (B_*T_)

typedef __hip_bfloat16 hbf;
typedef __bf16 bf16_t;
typedef bf16_t bf16x8 __attribute__((ext_vector_type(8)));
typedef bf16_t bf16x4 __attribute__((ext_vector_type(4)));
typedef float f32x4 __attribute__((ext_vector_type(4)));

static __device__ __forceinline__ void load_lds16(const void* g, void* l) {
    __builtin_amdgcn_global_load_lds(
        (const __attribute__((address_space(1))) unsigned int*)g,
        (__attribute__((address_space(3))) unsigned int*)l, 16, 0, 0);
}

// ---------------- LDS-tiled transpose: f32 [R][S] -> bf16 [S][R] ----------------
__global__ __launch_bounds__(256) void transpose_pack(
    const float* __restrict__ src, hbf* __restrict__ dst, int R, int S)
{
    __shared__ float tl[64 * 65];
    src += (size_t)blockIdx.z * R * S;
    dst += (size_t)blockIdx.z * R * S;
    const int r0 = blockIdx.y * 64, s0 = blockIdx.x * 64;
    const int c = threadIdx.x & 63, q = threadIdx.x >> 6;
#pragma unroll
    for (int j = 0; j < 16; ++j) {
        int r = q + j * 4;
        tl[r * 65 + c] = src[(size_t)(r0 + r) * S + s0 + c];
    }
    __syncthreads();
#pragma unroll
    for (int j = 0; j < 16; ++j) {
        int s = q + j * 4;
        dst[(size_t)(s0 + s) * R + r0 + c] = __float2bfloat16(tl[c * 65 + s]);
    }
}

// Combined q/k/v weight pack: 36 z-slices of [768][64] -> [64][768] bf16.
__global__ __launch_bounds__(256) void pack_qkv3(
    const float* __restrict__ Wq, const float* __restrict__ Wk,
    const float* __restrict__ Wv, hbf* __restrict__ WqkT, hbf* __restrict__ WvT)
{
    __shared__ float tl[64 * 65];
    const int z = blockIdx.z;
    const int mtx = z / 12, head = z - mtx * 12;
    const float* src = (mtx == 0 ? Wq : mtx == 1 ? Wk : Wv) + (size_t)head * 49152;
    hbf* dst = (mtx == 2) ? (WvT + (size_t)head * 49152)
                          : (WqkT + (size_t)(mtx * 12 + head) * 49152);
    const int r0 = blockIdx.y * 64;
    const int c = threadIdx.x & 63, q = threadIdx.x >> 6;
#pragma unroll
    for (int j = 0; j < 16; ++j) {
        int r = q + j * 4;
        tl[r * 65 + c] = src[(size_t)(r0 + r) * 64 + c];
    }
    __syncthreads();
#pragma unroll
    for (int j = 0; j < 16; ++j) {
        int s = q + j * 4;
        dst[(size_t)s * 768 + r0 + c] = __float2bfloat16(tl[c * 65 + s]);
    }
}

// ---------------- layernorm (row = 768) ----------------
__global__ __launch_bounds__(256) void ln_kernel(
    const float* __restrict__ x, const float* __restrict__ g,
    const float* __restrict__ bb, hbf* __restrict__ out)
{
    __shared__ float red[8];
    const int row = blockIdx.x;
    const float* xr = x + (size_t)row * C_;
    const int t = threadIdx.x;
    float v0 = xr[t], v1 = xr[t + 256], v2 = xr[t + 512];
    float s = v0 + v1 + v2;
    float s2 = v0 * v0 + v1 * v1 + v2 * v2;
#pragma unroll
    for (int m = 1; m < 64; m <<= 1) {
        s  += __shfl_xor(s,  m, 64);
        s2 += __shfl_xor(s2, m, 64);
    }
    if ((t & 63) == 0) { red[t >> 6] = s; red[4 + (t >> 6)] = s2; }
    __syncthreads();
    float S  = red[0] + red[1] + red[2] + red[3];
    float S2 = red[4] + red[5] + red[6] + red[7];
    float mu  = S * (1.0f / C_);
    float var = S2 * (1.0f / C_) - mu * mu;
    float inv = rsqrtf(var + 1e-6f);
    hbf* orow = out + (size_t)row * C_;
    orow[t]       = __float2bfloat16((v0 - mu) * inv * g[t]       + bb[t]);
    orow[t + 256] = __float2bfloat16((v1 - mu) * inv * g[t + 256] + bb[t + 256]);
    orow[t + 512] = __float2bfloat16((v2 - mu) * inv * g[t + 512] + bb[t + 512]);
}

// ---------------- GEMM: C[M,N] = A[M,K](bf16) * Bt[N,K](bf16)^T ----------------
// BK=64, tile 128xTN (TN=128 or 64), XOR-swizzled LDS, single buffer,
// m97-style 2-barrier loop, 1D grid + XCD swizzle.
// TN=128: 4 waves, wave owns 64x64 (4m x 4n).  TN=64: wave owns 32x64 (2m x 4n).
template<int EPI, int TN>
__global__ __launch_bounds__(256, 3) void gemm_kernel(
    const hbf* __restrict__ A, const hbf* __restrict__ Bt,
    float* __restrict__ outF, hbf* __restrict__ outH,
    const float* __restrict__ bias, const float* __restrict__ resid,
    int M, int N, int K,
    hbf* __restrict__ qb, hbf* __restrict__ kb,
    float scale, int gx)
{
    constexpr int AM = (TN == 128) ? 4 : 2;     // m-frags per wave
    constexpr int NB_B = (TN == 128) ? 4 : 2;   // B staging iters
    __shared__ hbf sA[128 * 64];
    __shared__ hbf sB[TN * 64];
    const int tid = threadIdx.x;
    const int lane = tid & 63;
    const int wid = tid >> 6;
    const int lr = lane & 15, hg = lane >> 4;
    const int bid = blockIdx.x, nwg = gridDim.x;
    const int wg = (bid & 7) * (nwg >> 3) + (bid >> 3);
    const int bx = wg % gx, by = wg / gx;
    const int row0 = by * 128;
    const int col0 = bx * TN;
    const int wrow = (TN == 128) ? (wid >> 1) * 64 : wid * 32;   // wave row base in tile
    const int wcol = (TN == 128) ? (wid & 1) * 64 : 0;

    f32x4 acc[AM][4] = {};

    int offG[4];
    const int Kb = K * 2;
#pragma unroll
    for (int i = 0; i < 4; ++i) {
        int c = tid + i * 256;
        offG[i] = (c >> 3) * Kb + (((c & 7) ^ ((c >> 3) & 7)) << 4);
    }
    const char* gA = (const char*)(A + (size_t)row0 * K);
    const char* gB = (const char*)(Bt + (size_t)col0 * K);

    auto stage = [&](int kt) {
        const int kb2 = kt * 128;
#pragma unroll
        for (int i = 0; i < 4; ++i)
            load_lds16(gA + (size_t)(offG[i] + kb2), (char*)sA + i * 4096 + wid * 1024);
#pragma unroll
        for (int i = 0; i < NB_B; ++i)
            load_lds16(gB + (size_t)(offG[i] + kb2), (char*)sB + i * 4096 + wid * 1024);
    };

    const int NK = K >> 6;
    stage(0);
    for (int kt = 0; kt < NK; ++kt) {
        __syncthreads();   // drains staged loads (compiler emits vmcnt(0) at barrier)
#pragma unroll
        for (int kf = 0; kf < 2; ++kf) {
            const int sl = ((kf * 4 + hg) ^ (lr & 7)) << 4;
            bf16x8 af[AM], bfr[4];
#pragma unroll
            for (int m = 0; m < AM; ++m)
                af[m] = *(const bf16x8*)((const char*)sA + (wrow + m * 16 + lr) * 128 + sl);
#pragma unroll
            for (int n = 0; n < 4; ++n)
                bfr[n] = *(const bf16x8*)((const char*)sB + (wcol + n * 16 + lr) * 128 + sl);
#pragma unroll
            for (int m = 0; m < AM; ++m)
#pragma unroll
                for (int n = 0; n < 4; ++n)
                    acc[m][n] = __builtin_amdgcn_mfma_f32_16x16x32_bf16(af[m], bfr[n], acc[m][n], 0, 0, 0);
        }
        __syncthreads();   // all waves done reading before restage
        if (kt + 1 < NK) stage(kt + 1);
    }

#pragma unroll
    for (int m = 0; m < AM; ++m) {
#pragma unroll
        for (int n = 0; n < 4; ++n) {
#pragma unroll
            for (int j = 0; j < 4; ++j) {
                int row = row0 + wrow + m * 16 + hg * 4 + j;
                int col = col0 + wcol + n * 16 + lr;
                float v = acc[m][n][j];
                if constexpr (EPI == 0) {
                    outH[(size_t)row * N + col] = __float2bfloat16(v);
                } else if constexpr (EPI == 1) {
                    outF[(size_t)row * N + col] = v + bias[col] + resid[(size_t)row * N + col];
                } else if constexpr (EPI == 2) {
                    float tt = v + bias[col];
                    float ge = 0.5f * tt * (1.0f + erff(tt * 0.70710678118654752f));
                    outH[(size_t)row * N + col] = __float2bfloat16(ge);
                } else {
                    int typ = col / C_;            // 0=q, 1=k
                    int rr = col - typ * C_;
                    int h = rr >> 6, d = rr & 63;
                    int b = row >> 11, t = row & (T_ - 1);
                    size_t bh = (size_t)b * H_ + h;
                    if (typ == 0) qb[(bh * T_ + t) * D_ + d] = __float2bfloat16(v * scale);
                    else          kb[(bh * T_ + t) * D_ + d] = __float2bfloat16(v);
                }
            }
        }
    }
}

// ---------------- flash attention (swapped QK^T, defer-max, __expf) ------------
// 1D grid 768 (XCD-swizzled). 4 waves x 32 q-rows. q pre-scaled by 768^-0.5.
// vT is [hd=768][B*T=8192]. LDS 48 KB -> 3 blocks/CU.  (r6-verified structure)
__global__ __launch_bounds__(256, 3) void attn_kernel(
    const hbf* __restrict__ qg, const hbf* __restrict__ kg,
    const hbf* __restrict__ vg, hbf* __restrict__ outA)
{
    __shared__ hbf sK0[64 * 64], sK1[64 * 64];   // [s][d], swizzled
    __shared__ hbf sV0[64 * 64], sV1[64 * 64];   // [d][s], swizzled
    __shared__ hbf sP[4 * 32 * 64];              // per wave [q=32][kv=64], swizzled
    const int tid = threadIdx.x, lane = tid & 63, wid = tid >> 6;
    const int lr = lane & 15, hg = lane >> 4;
    const int wg = (blockIdx.x & 7) * 96 + (blockIdx.x >> 3);   // 768/8 = 96
    const int bh = wg >> 4;
    const int b = bh / H_, h = bh - b * H_;
    const int wr0 = (wg & 15) * 128 + wid * 32;
    const hbf* qbh = qg + (size_t)bh * T_ * D_;
    const hbf* kbh = kg + (size_t)bh * T_ * D_;
    const hbf* vbh = vg + (size_t)h * 64 * BT_ + (size_t)b * T_;

    bf16x8 a_q[2][2];
#pragma unroll
    for (int m = 0; m < 2; ++m)
#pragma unroll
        for (int kf = 0; kf < 2; ++kf)
            a_q[m][kf] = *(const bf16x8*)(qbh + (size_t)(wr0 + m * 16 + lr) * D_ + kf * 32 + hg * 8);

    f32x4 o[2][4] = {};
    float mreg[2] = {-3e38f, -3e38f};
    float lrun[2] = {0.0f, 0.0f};

    int offK[2], offV[2];
#pragma unroll
    for (int i = 0; i < 2; ++i) {
        int c = tid + i * 256;
        int sw = ((c & 7) ^ ((c >> 3) & 7)) << 4;
        offK[i] = (c >> 3) * 128 + sw;
        offV[i] = (c >> 3) * (BT_ * 2) + sw;
    }
    hbf* sPw = sP + wid * (32 * 64);
    const int sl0 = ((0 * 4 + hg) ^ (lr & 7)) << 4;
    const int sl1 = ((1 * 4 + hg) ^ (lr & 7)) << 4;
    const int bcast = hg * 20;

    auto stage = [&](int itn, hbf* sKd, hbf* sVd) {
        const char* kp = (const char*)kbh + (size_t)itn * 8192;
        const char* vp = (const char*)vbh + (size_t)itn * 128;
#pragma unroll
        for (int i = 0; i < 2; ++i) {
            load_lds16(kp + offK[i], (char*)sKd + i * 4096 + wid * 1024);
            load_lds16(vp + offV[i], (char*)sVd + i * 4096 + wid * 1024);
        }
    };

    auto tile = [&](const hbf* sKc, const hbf* sVc) {
        f32x4 st[4][2] = {};
        __builtin_amdgcn_s_setprio(1);
#pragma unroll
        for (int kf = 0; kf < 2; ++kf) {
            const int sl = kf ? sl1 : sl0;
#pragma unroll
            for (int n = 0; n < 4; ++n) {
                bf16x8 ak = *(const bf16x8*)((const char*)sKc + (n * 16 + lr) * 128 + sl);
                st[n][0] = __builtin_amdgcn_mfma_f32_16x16x32_bf16(ak, a_q[0][kf], st[n][0], 0, 0, 0);
                st[n][1] = __builtin_amdgcn_mfma_f32_16x16x32_bf16(ak, a_q[1][kf], st[n][1], 0, 0, 0);
            }
        }
        __builtin_amdgcn_s_setprio(0);

#pragma unroll
        for (int m = 0; m < 2; ++m) {
            float t = st[0][m][0];
#pragma unroll
            for (int n = 0; n < 4; ++n)
#pragma unroll
                for (int j = 0; j < 4; ++j)
                    if (n + j > 0) t = fmaxf(t, st[n][m][j]);
            t = fmaxf(t, __shfl_xor(t, 16, 64));
            t = fmaxf(t, __shfl_xor(t, 32, 64));
            if (__any(t - mreg[m] > 8.0f)) {       // defer-max: rarely taken
                float nm = fmaxf(mreg[m], t);
                float fac = __expf(mreg[m] - nm);
                mreg[m] = nm;
                lrun[m] *= fac;
                float fb[4];
#pragma unroll
                for (int j = 0; j < 4; ++j)
                    fb[j] = __shfl(fac, bcast + j, 64);
#pragma unroll
                for (int nd = 0; nd < 4; ++nd)
#pragma unroll
                    for (int j = 0; j < 4; ++j)
                        o[m][nd][j] *= fb[j];
            }
            float ps = 0.0f;
            const int r = m * 16 + lr;
#pragma unroll
            for (int n = 0; n < 4; ++n) {
                float p0 = __expf(st[n][m][0] - mreg[m]);
                float p1 = __expf(st[n][m][1] - mreg[m]);
                float p2 = __expf(st[n][m][2] - mreg[m]);
                float p3 = __expf(st[n][m][3] - mreg[m]);
                ps += (p0 + p1) + (p2 + p3);
                bf16x4 w;
                w[0] = (bf16_t)p0; w[1] = (bf16_t)p1; w[2] = (bf16_t)p2; w[3] = (bf16_t)p3;
                *(bf16x4*)((char*)sPw + r * 128 +
                           (((n * 2 + (hg >> 1)) ^ (r & 7)) << 4) + ((hg & 1) * 8)) = w;
            }
            ps += __shfl_xor(ps, 16, 64);
            ps += __shfl_xor(ps, 32, 64);
            lrun[m] += ps;
        }

        __builtin_amdgcn_s_setprio(1);
#pragma unroll
        for (int kf = 0; kf < 2; ++kf) {
            const int sl = kf ? sl1 : sl0;
            bf16x8 ap0 = *(const bf16x8*)((const char*)sPw + lr * 128 + sl);
            bf16x8 ap1 = *(const bf16x8*)((const char*)sPw + (16 + lr) * 128 + sl);
#pragma unroll
            for (int nd = 0; nd < 4; ++nd) {
                bf16x8 bv = *(const bf16x8*)((const char*)sVc + (nd * 16 + lr) * 128 + sl);
                o[0][nd] = __builtin_amdgcn_mfma_f32_16x16x32_bf16(ap0, bv, o[0][nd], 0, 0, 0);
                o[1][nd] = __builtin_amdgcn_mfma_f32_16x16x32_bf16(ap1, bv, o[1][nd], 0, 0, 0);
            }
        }
        __builtin_amdgcn_s_setprio(0);
    };

    const int NT = T_ / 64;   // 32, even
    stage(0, sK0, sV0);
    __syncthreads();
    for (int it = 0; it < NT; it += 2) {
        stage(it + 1, sK1, sV1);
        tile(sK0, sV0);
        __syncthreads();
        if (it + 2 < NT) stage(it + 2, sK0, sV0);
        tile(sK1, sV1);
        __syncthreads();
    }

    float lb[2][4];
#pragma unroll
    for (int m = 0; m < 2; ++m)
#pragma unroll
        for (int j = 0; j < 4; ++j)
            lb[m][j] = __shfl(lrun[m], bcast + j, 64);
#pragma unroll
    for (int m = 0; m < 2; ++m)
#pragma unroll
        for (int nd = 0; nd < 4; ++nd)
#pragma unroll
            for (int j = 0; j < 4; ++j) {
                int row = wr0 + m * 16 + hg * 4 + j;
                int col = nd * 16 + lr;
                float val = o[m][nd][j] / lb[m][j];
                outA[((size_t)(b * T_ + row)) * C_ + h * D_ + col] = __float2bfloat16(val);
            }
}

// ---------------- launch ----------------
extern "C" void kernel_launch(void* const* d_in, const int* in_sizes, int n_in,
                              void* d_out, int out_size, void* d_ws, size_t ws_size,
                              hipStream_t stream)
{
    const float* x    = (const float*)d_in[0];
    const float* Wq   = (const float*)d_in[1];
    const float* Wk   = (const float*)d_in[2];
    const float* Wv   = (const float*)d_in[3];
    const float* Wo   = (const float*)d_in[4];
    const float* bo   = (const float*)d_in[5];
    const float* ln1g = (const float*)d_in[6];
    const float* ln1b = (const float*)d_in[7];
    const float* ln2g = (const float*)d_in[8];
    const float* ln2b = (const float*)d_in[9];
    const float* W1   = (const float*)d_in[10];
    const float* b1   = (const float*)d_in[11];
    const float* W2   = (const float*)d_in[12];
    const float* b2   = (const float*)d_in[13];
    float* out = (float*)d_out;
    char* ws = (char*)d_ws;

    hbf*  xn    = (hbf*)(ws + 0);            // 12.58 MB
    hbf*  WqkT  = (hbf*)(ws + 12582912);     // [1536][768] 2.36 MB
    hbf*  WvT   = (hbf*)(ws + 14942208);     // [768][768]  1.18 MB
    hbf*  qb    = (hbf*)(ws + 16121856);     // 12.58 MB
    hbf*  kb    = (hbf*)(ws + 28704768);     // 12.58 MB
    hbf*  vT    = (hbf*)(ws + 41287680);     // [768][8192] 12.58 MB
    hbf*  h1    = (hbf*)(ws + 0);            // 50.33 MB overlay (dead inputs by MLP)
    hbf*  attnB = (hbf*)(ws + 53870592);     // 12.58 MB
    hbf*  yln   = (hbf*)(ws + 53870592);     // overlays attnB
    float* x2   = (float*)(ws + 66453504);   // 25.17 MB
    hbf*  WoT   = (hbf*)(ws + 91619328);     // 1.18 MB
    hbf*  W1T   = (hbf*)(ws + 92798976);     // 4.72 MB
    hbf*  W2T   = (hbf*)(ws + 97517568);     // 4.72 MB (end 102,236,160)

    const float SCALE = 0.036084391824351615f;  // 768^-0.5

    pack_qkv3<<<dim3(1, 12, 36), 256, 0, stream>>>(Wq, Wk, Wv, WqkT, WvT);
    transpose_pack<<<dim3(12, 12, 1), 256, 0, stream>>>(Wo, WoT, 768, 768);
    transpose_pack<<<dim3(48, 12, 1), 256, 0, stream>>>(W1, W1T, 768, 3072);
    transpose_pack<<<dim3(12, 48, 1), 256, 0, stream>>>(W2, W2T, 3072, 768);
    ln_kernel<<<8192, 256, 0, stream>>>(x, ln1g, ln1b, xn);
    gemm_kernel<3,128><<<768, 256, 0, stream>>>(xn, WqkT, nullptr, nullptr, nullptr, nullptr,
        8192, 1536, 768, qb, kb, SCALE, 12);
    gemm_kernel<0,128><<<384, 256, 0, stream>>>(WvT, xn, nullptr, vT, nullptr, nullptr,
        768, BT_, 768, nullptr, nullptr, 1.0f, 64);
    attn_kernel<<<768, 256, 0, stream>>>(qb, kb, vT, attnB);
    gemm_kernel<1,64><<<768, 256, 0, stream>>>(attnB, WoT, x2, nullptr, bo, x,
        8192, 768, 768, nullptr, nullptr, 1.0f, 12);
    ln_kernel<<<8192, 256, 0, stream>>>(x2, ln2g, ln2b, yln);
    gemm_kernel<2,128><<<1536, 256, 0, stream>>>(yln, W1T, nullptr, h1, b1, nullptr,
        8192, 3072, 768, nullptr, nullptr, 1.0f, 24);
    gemm_kernel<1,64><<<768, 256, 0, stream>>>(h1, W2T, out, nullptr, b2, x2,
        8192, 768, 3072, nullptr, nullptr, 1.0f, 12);
}

// Round 9
// 283.557 us; speedup vs baseline: 1.1005x; 1.0209x over previous
//
#include <hip/hip_runtime.h>
#include <hip/hip_bf16.h>
#include <cstdint>
#include <cmath>

#define B_ 4
#define T_ 2048
#define C_ 768
#define H_ 12
#define D_ 64
#define MLP_ 3072
#define BT_ (B_*T_)

typedef __hip_bfloat16 hbf;
typedef __bf16 bf16_t;
typedef bf16_t bf16x8 __attribute__((ext_vector_type(8)));
typedef bf16_t bf16x4 __attribute__((ext_vector_type(4)));
typedef float f32x4 __attribute__((ext_vector_type(4)));

static __device__ __forceinline__ void load_lds16(const void* g, void* l) {
    __builtin_amdgcn_global_load_lds(
        (const __attribute__((address_space(1))) unsigned int*)g,
        (__attribute__((address_space(3))) unsigned int*)l, 16, 0, 0);
}

// ---------------- LDS-tiled transpose: f32 [R][S] -> bf16 [S][R] ----------------
__global__ __launch_bounds__(256) void transpose_pack(
    const float* __restrict__ src, hbf* __restrict__ dst, int R, int S)
{
    __shared__ float tl[64 * 65];
    src += (size_t)blockIdx.z * R * S;
    dst += (size_t)blockIdx.z * R * S;
    const int r0 = blockIdx.y * 64, s0 = blockIdx.x * 64;
    const int c = threadIdx.x & 63, q = threadIdx.x >> 6;
#pragma unroll
    for (int j = 0; j < 16; ++j) {
        int r = q + j * 4;
        tl[r * 65 + c] = src[(size_t)(r0 + r) * S + s0 + c];
    }
    __syncthreads();
#pragma unroll
    for (int j = 0; j < 16; ++j) {
        int s = q + j * 4;
        dst[(size_t)(s0 + s) * R + r0 + c] = __float2bfloat16(tl[c * 65 + s]);
    }
}

// Combined q/k/v weight pack: 36 z-slices of [768][64] -> rows of WqkT [2304][768].
// z = mtx*12 + head: rows 0..767 = q, 768..1535 = k, 1536..2303 = v.
__global__ __launch_bounds__(256) void pack_qkv3(
    const float* __restrict__ Wq, const float* __restrict__ Wk,
    const float* __restrict__ Wv, hbf* __restrict__ WqkT)
{
    __shared__ float tl[64 * 65];
    const int z = blockIdx.z;
    const int mtx = z / 12, head = z - mtx * 12;
    const float* src = (mtx == 0 ? Wq : mtx == 1 ? Wk : Wv) + (size_t)head * 49152;
    hbf* dst = WqkT + (size_t)z * 49152;
    const int r0 = blockIdx.y * 64;
    const int c = threadIdx.x & 63, q = threadIdx.x >> 6;
#pragma unroll
    for (int j = 0; j < 16; ++j) {
        int r = q + j * 4;
        tl[r * 65 + c] = src[(size_t)(r0 + r) * 64 + c];
    }
    __syncthreads();
#pragma unroll
    for (int j = 0; j < 16; ++j) {
        int s = q + j * 4;
        dst[(size_t)s * 768 + r0 + c] = __float2bfloat16(tl[c * 65 + s]);
    }
}

// ---------------- layernorm (row = 768), templated input type ----------------
template<typename TI>
__global__ __launch_bounds__(256) void ln_kernel(
    const TI* __restrict__ x, const float* __restrict__ g,
    const float* __restrict__ bb, hbf* __restrict__ out)
{
    __shared__ float red[8];
    const int row = blockIdx.x;
    const TI* xr = x + (size_t)row * C_;
    const int t = threadIdx.x;
    float v0, v1, v2;
    if constexpr (__is_same(TI, float)) {
        v0 = xr[t]; v1 = xr[t + 256]; v2 = xr[t + 512];
    } else {
        v0 = __bfloat162float(xr[t]);
        v1 = __bfloat162float(xr[t + 256]);
        v2 = __bfloat162float(xr[t + 512]);
    }
    float s = v0 + v1 + v2;
    float s2 = v0 * v0 + v1 * v1 + v2 * v2;
#pragma unroll
    for (int m = 1; m < 64; m <<= 1) {
        s  += __shfl_xor(s,  m, 64);
        s2 += __shfl_xor(s2, m, 64);
    }
    if ((t & 63) == 0) { red[t >> 6] = s; red[4 + (t >> 6)] = s2; }
    __syncthreads();
    float S  = red[0] + red[1] + red[2] + red[3];
    float S2 = red[4] + red[5] + red[6] + red[7];
    float mu  = S * (1.0f / C_);
    float var = S2 * (1.0f / C_) - mu * mu;
    float inv = rsqrtf(var + 1e-6f);
    hbf* orow = out + (size_t)row * C_;
    orow[t]       = __float2bfloat16((v0 - mu) * inv * g[t]       + bb[t]);
    orow[t + 256] = __float2bfloat16((v1 - mu) * inv * g[t + 256] + bb[t + 256]);
    orow[t + 512] = __float2bfloat16((v2 - mu) * inv * g[t + 512] + bb[t + 512]);
}

// ---------------- GEMM: C[M,N] = A[M,K](bf16) * Bt[N,K](bf16)^T ----------------
// BK=64, tile 128xTN (TN=128 or 64), XOR-swizzled LDS, single buffer,
// 2-barrier loop, 1D grid + XCD swizzle. TN=64 runs 4 blocks/CU.
// EPI 0: bf16 plain            EPI 2: bf16 gelu(acc+bias)
// EPI 3: qkv scatter (N=2304: q scaled, k plain, v -> vT[hd][bt] coalesced)
// EPI 4: bf16 out = acc + bias + residF (f32)
// EPI 5: f32  out = acc + bias + residH (bf16)
template<int EPI, int TN>
__global__ __launch_bounds__(256, (TN == 64) ? 4 : 3) void gemm_kernel(
    const hbf* __restrict__ A, const hbf* __restrict__ Bt,
    float* __restrict__ outF, hbf* __restrict__ outH,
    const float* __restrict__ bias, const float* __restrict__ residF,
    const hbf* __restrict__ residH,
    int M, int N, int K,
    hbf* __restrict__ qb, hbf* __restrict__ kb, hbf* __restrict__ vt,
    float scale, int gx)
{
    constexpr int AM = (TN == 128) ? 4 : 2;     // m-frags per wave
    constexpr int NB_B = (TN == 128) ? 4 : 2;   // B staging iters
    __shared__ hbf sA[128 * 64];
    __shared__ hbf sB[TN * 64];
    const int tid = threadIdx.x;
    const int lane = tid & 63;
    const int wid = tid >> 6;
    const int lr = lane & 15, hg = lane >> 4;
    const int bid = blockIdx.x, nwg = gridDim.x;
    const int wg = (bid & 7) * (nwg >> 3) + (bid >> 3);
    const int bx = wg % gx, by = wg / gx;
    const int row0 = by * 128;
    const int col0 = bx * TN;
    const int wrow = (TN == 128) ? (wid >> 1) * 64 : wid * 32;
    const int wcol = (TN == 128) ? (wid & 1) * 64 : 0;

    f32x4 acc[AM][4] = {};

    int offG[4];
    const int Kb = K * 2;
#pragma unroll
    for (int i = 0; i < 4; ++i) {
        int c = tid + i * 256;
        offG[i] = (c >> 3) * Kb + (((c & 7) ^ ((c >> 3) & 7)) << 4);
    }
    const char* gA = (const char*)(A + (size_t)row0 * K);
    const char* gB = (const char*)(Bt + (size_t)col0 * K);

    auto stage = [&](int kt) {
        const int kb2 = kt * 128;
#pragma unroll
        for (int i = 0; i < 4; ++i)
            load_lds16(gA + (size_t)(offG[i] + kb2), (char*)sA + i * 4096 + wid * 1024);
#pragma unroll
        for (int i = 0; i < NB_B; ++i)
            load_lds16(gB + (size_t)(offG[i] + kb2), (char*)sB + i * 4096 + wid * 1024);
    };

    const int NK = K >> 6;
    stage(0);
    for (int kt = 0; kt < NK; ++kt) {
        __syncthreads();   // drains staged loads
#pragma unroll
        for (int kf = 0; kf < 2; ++kf) {
            const int sl = ((kf * 4 + hg) ^ (lr & 7)) << 4;
            bf16x8 af[AM], bfr[4];
#pragma unroll
            for (int m = 0; m < AM; ++m)
                af[m] = *(const bf16x8*)((const char*)sA + (wrow + m * 16 + lr) * 128 + sl);
#pragma unroll
            for (int n = 0; n < 4; ++n)
                bfr[n] = *(const bf16x8*)((const char*)sB + (wcol + n * 16 + lr) * 128 + sl);
#pragma unroll
            for (int m = 0; m < AM; ++m)
#pragma unroll
                for (int n = 0; n < 4; ++n)
                    acc[m][n] = __builtin_amdgcn_mfma_f32_16x16x32_bf16(af[m], bfr[n], acc[m][n], 0, 0, 0);
        }
        __syncthreads();   // all waves done reading before restage
        if (kt + 1 < NK) stage(kt + 1);
    }

#pragma unroll
    for (int m = 0; m < AM; ++m) {
#pragma unroll
        for (int n = 0; n < 4; ++n) {
            const int colc = col0 + wcol + n * 16 + lr;
            const int rowb = row0 + wrow + m * 16 + hg * 4;
            if constexpr (EPI == 3) {
                // v columns: 4 consecutive rows -> one bf16x4 store into vT[hd][bt]
                if (colc >= 2 * C_) {
                    bf16x4 w;
#pragma unroll
                    for (int j = 0; j < 4; ++j) w[j] = (bf16_t)acc[m][n][j];
                    *(bf16x4*)(vt + (size_t)(colc - 2 * C_) * BT_ + rowb) = w;
                    continue;
                }
            }
#pragma unroll
            for (int j = 0; j < 4; ++j) {
                int row = rowb + j;
                int col = colc;
                float v = acc[m][n][j];
                if constexpr (EPI == 0) {
                    outH[(size_t)row * N + col] = __float2bfloat16(v);
                } else if constexpr (EPI == 2) {
                    float tt = v + bias[col];
                    float ge = 0.5f * tt * (1.0f + erff(tt * 0.70710678118654752f));
                    outH[(size_t)row * N + col] = __float2bfloat16(ge);
                } else if constexpr (EPI == 3) {
                    int typ = col / C_;            // 0=q, 1=k (v handled above)
                    int rr = col - typ * C_;
                    int h = rr >> 6, d = rr & 63;
                    int b = row >> 11, t = row & (T_ - 1);
                    size_t bh = (size_t)b * H_ + h;
                    if (typ == 0) qb[(bh * T_ + t) * D_ + d] = __float2bfloat16(v * scale);
                    else          kb[(bh * T_ + t) * D_ + d] = __float2bfloat16(v);
                } else if constexpr (EPI == 4) {
                    outH[(size_t)row * N + col] =
                        __float2bfloat16(v + bias[col] + residF[(size_t)row * N + col]);
                } else {  // EPI == 5
                    outF[(size_t)row * N + col] =
                        v + bias[col] + __bfloat162float(residH[(size_t)row * N + col]);
                }
            }
        }
    }
}

// ---------------- flash attention (swapped QK^T, defer-max, __expf) ------------
// 1D grid 768 (XCD-swizzled). 4 waves x 32 q-rows. q pre-scaled by 768^-0.5.
// vT is [hd=768][B*T=8192]. LDS 48 KB -> 3 blocks/CU.  (r6-verified structure)
__global__ __launch_bounds__(256, 3) void attn_kernel(
    const hbf* __restrict__ qg, const hbf* __restrict__ kg,
    const hbf* __restrict__ vg, hbf* __restrict__ outA)
{
    __shared__ hbf sK0[64 * 64], sK1[64 * 64];   // [s][d], swizzled
    __shared__ hbf sV0[64 * 64], sV1[64 * 64];   // [d][s], swizzled
    __shared__ hbf sP[4 * 32 * 64];              // per wave [q=32][kv=64], swizzled
    const int tid = threadIdx.x, lane = tid & 63, wid = tid >> 6;
    const int lr = lane & 15, hg = lane >> 4;
    const int wg = (blockIdx.x & 7) * 96 + (blockIdx.x >> 3);   // 768/8 = 96
    const int bh = wg >> 4;
    const int b = bh / H_, h = bh - b * H_;
    const int wr0 = (wg & 15) * 128 + wid * 32;
    const hbf* qbh = qg + (size_t)bh * T_ * D_;
    const hbf* kbh = kg + (size_t)bh * T_ * D_;
    const hbf* vbh = vg + (size_t)h * 64 * BT_ + (size_t)b * T_;

    bf16x8 a_q[2][2];
#pragma unroll
    for (int m = 0; m < 2; ++m)
#pragma unroll
        for (int kf = 0; kf < 2; ++kf)
            a_q[m][kf] = *(const bf16x8*)(qbh + (size_t)(wr0 + m * 16 + lr) * D_ + kf * 32 + hg * 8);

    f32x4 o[2][4] = {};
    float mreg[2] = {-3e38f, -3e38f};
    float lrun[2] = {0.0f, 0.0f};

    int offK[2], offV[2];
#pragma unroll
    for (int i = 0; i < 2; ++i) {
        int c = tid + i * 256;
        int sw = ((c & 7) ^ ((c >> 3) & 7)) << 4;
        offK[i] = (c >> 3) * 128 + sw;
        offV[i] = (c >> 3) * (BT_ * 2) + sw;
    }
    hbf* sPw = sP + wid * (32 * 64);
    const int sl0 = ((0 * 4 + hg) ^ (lr & 7)) << 4;
    const int sl1 = ((1 * 4 + hg) ^ (lr & 7)) << 4;
    const int bcast = hg * 20;

    auto stage = [&](int itn, hbf* sKd, hbf* sVd) {
        const char* kp = (const char*)kbh + (size_t)itn * 8192;
        const char* vp = (const char*)vbh + (size_t)itn * 128;
#pragma unroll
        for (int i = 0; i < 2; ++i) {
            load_lds16(kp + offK[i], (char*)sKd + i * 4096 + wid * 1024);
            load_lds16(vp + offV[i], (char*)sVd + i * 4096 + wid * 1024);
        }
    };

    auto tile = [&](const hbf* sKc, const hbf* sVc) {
        f32x4 st[4][2] = {};
        __builtin_amdgcn_s_setprio(1);
#pragma unroll
        for (int kf = 0; kf < 2; ++kf) {
            const int sl = kf ? sl1 : sl0;
#pragma unroll
            for (int n = 0; n < 4; ++n) {
                bf16x8 ak = *(const bf16x8*)((const char*)sKc + (n * 16 + lr) * 128 + sl);
                st[n][0] = __builtin_amdgcn_mfma_f32_16x16x32_bf16(ak, a_q[0][kf], st[n][0], 0, 0, 0);
                st[n][1] = __builtin_amdgcn_mfma_f32_16x16x32_bf16(ak, a_q[1][kf], st[n][1], 0, 0, 0);
            }
        }
        __builtin_amdgcn_s_setprio(0);

#pragma unroll
        for (int m = 0; m < 2; ++m) {
            float t = st[0][m][0];
#pragma unroll
            for (int n = 0; n < 4; ++n)
#pragma unroll
                for (int j = 0; j < 4; ++j)
                    if (n + j > 0) t = fmaxf(t, st[n][m][j]);
            t = fmaxf(t, __shfl_xor(t, 16, 64));
            t = fmaxf(t, __shfl_xor(t, 32, 64));
            if (__any(t - mreg[m] > 8.0f)) {       // defer-max: rarely taken
                float nm = fmaxf(mreg[m], t);
                float fac = __expf(mreg[m] - nm);
                mreg[m] = nm;
                lrun[m] *= fac;
                float fb[4];
#pragma unroll
                for (int j = 0; j < 4; ++j)
                    fb[j] = __shfl(fac, bcast + j, 64);
#pragma unroll
                for (int nd = 0; nd < 4; ++nd)
#pragma unroll
                    for (int j = 0; j < 4; ++j)
                        o[m][nd][j] *= fb[j];
            }
            float ps = 0.0f;
            const int r = m * 16 + lr;
#pragma unroll
            for (int n = 0; n < 4; ++n) {
                float p0 = __expf(st[n][m][0] - mreg[m]);
                float p1 = __expf(st[n][m][1] - mreg[m]);
                float p2 = __expf(st[n][m][2] - mreg[m]);
                float p3 = __expf(st[n][m][3] - mreg[m]);
                ps += (p0 + p1) + (p2 + p3);
                bf16x4 w;
                w[0] = (bf16_t)p0; w[1] = (bf16_t)p1; w[2] = (bf16_t)p2; w[3] = (bf16_t)p3;
                *(bf16x4*)((char*)sPw + r * 128 +
                           (((n * 2 + (hg >> 1)) ^ (r & 7)) << 4) + ((hg & 1) * 8)) = w;
            }
            ps += __shfl_xor(ps, 16, 64);
            ps += __shfl_xor(ps, 32, 64);
            lrun[m] += ps;
        }

        __builtin_amdgcn_s_setprio(1);
#pragma unroll
        for (int kf = 0; kf < 2; ++kf) {
            const int sl = kf ? sl1 : sl0;
            bf16x8 ap0 = *(const bf16x8*)((const char*)sPw + lr * 128 + sl);
            bf16x8 ap1 = *(const bf16x8*)((const char*)sPw + (16 + lr) * 128 + sl);
#pragma unroll
            for (int nd = 0; nd < 4; ++nd) {
                bf16x8 bv = *(const bf16x8*)((const char*)sVc + (nd * 16 + lr) * 128 + sl);
                o[0][nd] = __builtin_amdgcn_mfma_f32_16x16x32_bf16(ap0, bv, o[0][nd], 0, 0, 0);
                o[1][nd] = __builtin_amdgcn_mfma_f32_16x16x32_bf16(ap1, bv, o[1][nd], 0, 0, 0);
            }
        }
        __builtin_amdgcn_s_setprio(0);
    };

    const int NT = T_ / 64;   // 32, even
    stage(0, sK0, sV0);
    __syncthreads();
    for (int it = 0; it < NT; it += 2) {
        stage(it + 1, sK1, sV1);
        tile(sK0, sV0);
        __syncthreads();
        if (it + 2 < NT) stage(it + 2, sK0, sV0);
        tile(sK1, sV1);
        __syncthreads();
    }

    float lb[2][4];
#pragma unroll
    for (int m = 0; m < 2; ++m)
#pragma unroll
        for (int j = 0; j < 4; ++j)
            lb[m][j] = __shfl(lrun[m], bcast + j, 64);
#pragma unroll
    for (int m = 0; m < 2; ++m)
#pragma unroll
        for (int nd = 0; nd < 4; ++nd)
#pragma unroll
            for (int j = 0; j < 4; ++j) {
                int row = wr0 + m * 16 + hg * 4 + j;
                int col = nd * 16 + lr;
                float val = o[m][nd][j] / lb[m][j];
                outA[((size_t)(b * T_ + row)) * C_ + h * D_ + col] = __float2bfloat16(val);
            }
}

// ---------------- launch ----------------
extern "C" void kernel_launch(void* const* d_in, const int* in_sizes, int n_in,
                              void* d_out, int out_size, void* d_ws, size_t ws_size,
                              hipStream_t stream)
{
    const float* x    = (const float*)d_in[0];
    const float* Wq   = (const float*)d_in[1];
    const float* Wk   = (const float*)d_in[2];
    const float* Wv   = (const float*)d_in[3];
    const float* Wo   = (const float*)d_in[4];
    const float* bo   = (const float*)d_in[5];
    const float* ln1g = (const float*)d_in[6];
    const float* ln1b = (const float*)d_in[7];
    const float* ln2g = (const float*)d_in[8];
    const float* ln2b = (const float*)d_in[9];
    const float* W1   = (const float*)d_in[10];
    const float* b1   = (const float*)d_in[11];
    const float* W2   = (const float*)d_in[12];
    const float* b2   = (const float*)d_in[13];
    float* out = (float*)d_out;
    char* ws = (char*)d_ws;

    hbf*  xn    = (hbf*)(ws + 0);            // 12.58 MB
    hbf*  WqkT  = (hbf*)(ws + 12582912);     // [2304][768] 3.54 MB (q,k,v rows)
    hbf*  qb    = (hbf*)(ws + 16121856);     // 12.58 MB
    hbf*  kb    = (hbf*)(ws + 28704768);     // 12.58 MB
    hbf*  vT    = (hbf*)(ws + 41287680);     // [768][8192] 12.58 MB
    hbf*  h1    = (hbf*)(ws + 0);            // 50.33 MB overlay (dead inputs by MLP)
    hbf*  attnB = (hbf*)(ws + 53870592);     // 12.58 MB
    hbf*  yln   = (hbf*)(ws + 53870592);     // overlays attnB
    hbf*  x2b   = (hbf*)(ws + 66453504);     // 12.58 MB (bf16 residual-1)
    hbf*  WoT   = (hbf*)(ws + 91619328);     // 1.18 MB
    hbf*  W1T   = (hbf*)(ws + 92798976);     // 4.72 MB
    hbf*  W2T   = (hbf*)(ws + 97517568);     // 4.72 MB (end 102,236,160)

    const float SCALE = 0.036084391824351615f;  // 768^-0.5

    pack_qkv3<<<dim3(1, 12, 36), 256, 0, stream>>>(Wq, Wk, Wv, WqkT);
    transpose_pack<<<dim3(12, 12, 1), 256, 0, stream>>>(Wo, WoT, 768, 768);
    transpose_pack<<<dim3(48, 12, 1), 256, 0, stream>>>(W1, W1T, 768, 3072);
    transpose_pack<<<dim3(12, 48, 1), 256, 0, stream>>>(W2, W2T, 3072, 768);
    ln_kernel<float><<<8192, 256, 0, stream>>>(x, ln1g, ln1b, xn);
    // fused q/k/v projection (N=2304): q,k scatter + vT coalesced store
    gemm_kernel<3,128><<<1152, 256, 0, stream>>>(xn, WqkT, nullptr, nullptr, nullptr, nullptr,
        nullptr, 8192, 2304, 768, qb, kb, vT, SCALE, 18);
    attn_kernel<<<768, 256, 0, stream>>>(qb, kb, vT, attnB);
    // proj: x2b (bf16) = attnB.WoT + bo + x
    gemm_kernel<4,64><<<768, 256, 0, stream>>>(attnB, WoT, nullptr, x2b, bo, x,
        nullptr, 8192, 768, 768, nullptr, nullptr, nullptr, 1.0f, 12);
    ln_kernel<hbf><<<8192, 256, 0, stream>>>(x2b, ln2g, ln2b, yln);
    gemm_kernel<2,128><<<1536, 256, 0, stream>>>(yln, W1T, nullptr, h1, b1, nullptr,
        nullptr, 8192, 3072, 768, nullptr, nullptr, nullptr, 1.0f, 24);
    // mlp2: out (f32) = h1.W2T + b2 + x2b
    gemm_kernel<5,64><<<768, 256, 0, stream>>>(h1, W2T, out, nullptr, b2, nullptr,
        x2b, 8192, 768, 3072, nullptr, nullptr, nullptr, 1.0f, 12);
}

// Round 10
// 280.107 us; speedup vs baseline: 1.1141x; 1.0123x over previous
//
#include <hip/hip_runtime.h>
#include <hip/hip_bf16.h>
#include <cstdint>
#include <cmath>

#define B_ 4
#define T_ 2048
#define C_ 768
#define H_ 12
#define D_ 64
#define MLP_ 3072
#define BT_ (B_*T_)

typedef __hip_bfloat16 hbf;
typedef __bf16 bf16_t;
typedef bf16_t bf16x8 __attribute__((ext_vector_type(8)));
typedef bf16_t bf16x4 __attribute__((ext_vector_type(4)));
typedef float f32x4 __attribute__((ext_vector_type(4)));

static __device__ __forceinline__ void load_lds16(const void* g, void* l) {
    __builtin_amdgcn_global_load_lds(
        (const __attribute__((address_space(1))) unsigned int*)g,
        (__attribute__((address_space(3))) unsigned int*)l, 16, 0, 0);
}

// ---------------- LDS-tiled transpose: f32 [R][S] -> bf16 [S][R] ----------------
__global__ __launch_bounds__(256) void transpose_pack(
    const float* __restrict__ src, hbf* __restrict__ dst, int R, int S)
{
    __shared__ float tl[64 * 65];
    src += (size_t)blockIdx.z * R * S;
    dst += (size_t)blockIdx.z * R * S;
    const int r0 = blockIdx.y * 64, s0 = blockIdx.x * 64;
    const int c = threadIdx.x & 63, q = threadIdx.x >> 6;
#pragma unroll
    for (int j = 0; j < 16; ++j) {
        int r = q + j * 4;
        tl[r * 65 + c] = src[(size_t)(r0 + r) * S + s0 + c];
    }
    __syncthreads();
#pragma unroll
    for (int j = 0; j < 16; ++j) {
        int s = q + j * 4;
        dst[(size_t)(s0 + s) * R + r0 + c] = __float2bfloat16(tl[c * 65 + s]);
    }
}

// Combined q/k/v weight pack: 36 z-slices of [768][64] -> rows of WqkT [2304][768].
__global__ __launch_bounds__(256) void pack_qkv3(
    const float* __restrict__ Wq, const float* __restrict__ Wk,
    const float* __restrict__ Wv, hbf* __restrict__ WqkT)
{
    __shared__ float tl[64 * 65];
    const int z = blockIdx.z;
    const int mtx = z / 12, head = z - mtx * 12;
    const float* src = (mtx == 0 ? Wq : mtx == 1 ? Wk : Wv) + (size_t)head * 49152;
    hbf* dst = WqkT + (size_t)z * 49152;
    const int r0 = blockIdx.y * 64;
    const int c = threadIdx.x & 63, q = threadIdx.x >> 6;
#pragma unroll
    for (int j = 0; j < 16; ++j) {
        int r = q + j * 4;
        tl[r * 65 + c] = src[(size_t)(r0 + r) * 64 + c];
    }
    __syncthreads();
#pragma unroll
    for (int j = 0; j < 16; ++j) {
        int s = q + j * 4;
        dst[(size_t)s * 768 + r0 + c] = __float2bfloat16(tl[c * 65 + s]);
    }
}

// ---------------- layernorm (row = 768), templated input type ----------------
template<typename TI>
__global__ __launch_bounds__(256) void ln_kernel(
    const TI* __restrict__ x, const float* __restrict__ g,
    const float* __restrict__ bb, hbf* __restrict__ out)
{
    __shared__ float red[8];
    const int row = blockIdx.x;
    const TI* xr = x + (size_t)row * C_;
    const int t = threadIdx.x;
    float v0, v1, v2;
    if constexpr (__is_same(TI, float)) {
        v0 = xr[t]; v1 = xr[t + 256]; v2 = xr[t + 512];
    } else {
        v0 = __bfloat162float(xr[t]);
        v1 = __bfloat162float(xr[t + 256]);
        v2 = __bfloat162float(xr[t + 512]);
    }
    float s = v0 + v1 + v2;
    float s2 = v0 * v0 + v1 * v1 + v2 * v2;
#pragma unroll
    for (int m = 1; m < 64; m <<= 1) {
        s  += __shfl_xor(s,  m, 64);
        s2 += __shfl_xor(s2, m, 64);
    }
    if ((t & 63) == 0) { red[t >> 6] = s; red[4 + (t >> 6)] = s2; }
    __syncthreads();
    float S  = red[0] + red[1] + red[2] + red[3];
    float S2 = red[4] + red[5] + red[6] + red[7];
    float mu  = S * (1.0f / C_);
    float var = S2 * (1.0f / C_) - mu * mu;
    float inv = rsqrtf(var + 1e-6f);
    hbf* orow = out + (size_t)row * C_;
    orow[t]       = __float2bfloat16((v0 - mu) * inv * g[t]       + bb[t]);
    orow[t + 256] = __float2bfloat16((v1 - mu) * inv * g[t + 256] + bb[t + 256]);
    orow[t + 512] = __float2bfloat16((v2 - mu) * inv * g[t + 512] + bb[t + 512]);
}

// ---------------- GEMM: C[M,N] = A[M,K](bf16) * Bt[N,K](bf16)^T ----------------
// BK=64, tile 128xTN (TN=128 or 64), XOR-swizzled LDS, single buffer,
// 2-barrier loop, 1D grid + XCD swizzle. TN=64 runs 4 blocks/CU.
template<int EPI, int TN>
__global__ __launch_bounds__(256, (TN == 64) ? 4 : 3) void gemm_kernel(
    const hbf* __restrict__ A, const hbf* __restrict__ Bt,
    float* __restrict__ outF, hbf* __restrict__ outH,
    const float* __restrict__ bias, const float* __restrict__ residF,
    const hbf* __restrict__ residH,
    int M, int N, int K,
    hbf* __restrict__ qb, hbf* __restrict__ kb, hbf* __restrict__ vt,
    float scale, int gx)
{
    constexpr int AM = (TN == 128) ? 4 : 2;     // m-frags per wave
    constexpr int NB_B = (TN == 128) ? 4 : 2;   // B staging iters
    __shared__ hbf sA[128 * 64];
    __shared__ hbf sB[TN * 64];
    const int tid = threadIdx.x;
    const int lane = tid & 63;
    const int wid = tid >> 6;
    const int lr = lane & 15, hg = lane >> 4;
    const int bid = blockIdx.x, nwg = gridDim.x;
    const int wg = (bid & 7) * (nwg >> 3) + (bid >> 3);
    const int bx = wg % gx, by = wg / gx;
    const int row0 = by * 128;
    const int col0 = bx * TN;
    const int wrow = (TN == 128) ? (wid >> 1) * 64 : wid * 32;
    const int wcol = (TN == 128) ? (wid & 1) * 64 : 0;

    f32x4 acc[AM][4] = {};

    int offG[4];
    const int Kb = K * 2;
#pragma unroll
    for (int i = 0; i < 4; ++i) {
        int c = tid + i * 256;
        offG[i] = (c >> 3) * Kb + (((c & 7) ^ ((c >> 3) & 7)) << 4);
    }
    const char* gA = (const char*)(A + (size_t)row0 * K);
    const char* gB = (const char*)(Bt + (size_t)col0 * K);

    auto stage = [&](int kt) {
        const int kb2 = kt * 128;
#pragma unroll
        for (int i = 0; i < 4; ++i)
            load_lds16(gA + (size_t)(offG[i] + kb2), (char*)sA + i * 4096 + wid * 1024);
#pragma unroll
        for (int i = 0; i < NB_B; ++i)
            load_lds16(gB + (size_t)(offG[i] + kb2), (char*)sB + i * 4096 + wid * 1024);
    };

    const int NK = K >> 6;
    stage(0);
    for (int kt = 0; kt < NK; ++kt) {
        __syncthreads();   // drains staged loads
#pragma unroll
        for (int kf = 0; kf < 2; ++kf) {
            const int sl = ((kf * 4 + hg) ^ (lr & 7)) << 4;
            bf16x8 af[AM], bfr[4];
#pragma unroll
            for (int m = 0; m < AM; ++m)
                af[m] = *(const bf16x8*)((const char*)sA + (wrow + m * 16 + lr) * 128 + sl);
#pragma unroll
            for (int n = 0; n < 4; ++n)
                bfr[n] = *(const bf16x8*)((const char*)sB + (wcol + n * 16 + lr) * 128 + sl);
#pragma unroll
            for (int m = 0; m < AM; ++m)
#pragma unroll
                for (int n = 0; n < 4; ++n)
                    acc[m][n] = __builtin_amdgcn_mfma_f32_16x16x32_bf16(af[m], bfr[n], acc[m][n], 0, 0, 0);
        }
        __syncthreads();   // all waves done reading before restage
        if (kt + 1 < NK) stage(kt + 1);
    }

#pragma unroll
    for (int m = 0; m < AM; ++m) {
#pragma unroll
        for (int n = 0; n < 4; ++n) {
            const int colc = col0 + wcol + n * 16 + lr;
            const int rowb = row0 + wrow + m * 16 + hg * 4;
            if constexpr (EPI == 3) {
                if (colc >= 2 * C_) {
                    bf16x4 w;
#pragma unroll
                    for (int j = 0; j < 4; ++j) w[j] = (bf16_t)acc[m][n][j];
                    *(bf16x4*)(vt + (size_t)(colc - 2 * C_) * BT_ + rowb) = w;
                    continue;
                }
            }
#pragma unroll
            for (int j = 0; j < 4; ++j) {
                int row = rowb + j;
                int col = colc;
                float v = acc[m][n][j];
                if constexpr (EPI == 0) {
                    outH[(size_t)row * N + col] = __float2bfloat16(v);
                } else if constexpr (EPI == 2) {
                    float tt = v + bias[col];
                    float ge = 0.5f * tt * (1.0f + erff(tt * 0.70710678118654752f));
                    outH[(size_t)row * N + col] = __float2bfloat16(ge);
                } else if constexpr (EPI == 3) {
                    int typ = col / C_;            // 0=q, 1=k (v handled above)
                    int rr = col - typ * C_;
                    int h = rr >> 6, d = rr & 63;
                    int b = row >> 11, t = row & (T_ - 1);
                    size_t bh = (size_t)b * H_ + h;
                    if (typ == 0) qb[(bh * T_ + t) * D_ + d] = __float2bfloat16(v * scale);
                    else          kb[(bh * T_ + t) * D_ + d] = __float2bfloat16(v);
                } else if constexpr (EPI == 4) {
                    outH[(size_t)row * N + col] =
                        __float2bfloat16(v + bias[col] + residF[(size_t)row * N + col]);
                } else {  // EPI == 5
                    outF[(size_t)row * N + col] =
                        v + bias[col] + __bfloat162float(residH[(size_t)row * N + col]);
                }
            }
        }
    }
}

// ---------------- flash attention (swapped QK^T, defer-max, MFMA row-sum) ------
// 1D grid 768 (XCD-swizzled). 4 waves x 32 q-rows. q pre-scaled by 768^-0.5.
// vT is [hd=768][B*T=8192]. LDS 48 KB -> 3 blocks/CU.
// Softmax denominator l = P.1 accumulated via MFMA against a ones-B-fragment:
// l's C/D layout (row=hg*4+j) matches o's, so NO cross-lane broadcast for the
// psum reduce or the epilogue division (removes 4 shfls/tile + 8 in epilogue).
__global__ __launch_bounds__(256, 3) void attn_kernel(
    const hbf* __restrict__ qg, const hbf* __restrict__ kg,
    const hbf* __restrict__ vg, hbf* __restrict__ outA)
{
    __shared__ hbf sK0[64 * 64], sK1[64 * 64];   // [s][d], swizzled
    __shared__ hbf sV0[64 * 64], sV1[64 * 64];   // [d][s], swizzled
    __shared__ hbf sP[4 * 32 * 64];              // per wave [q=32][kv=64], swizzled
    const int tid = threadIdx.x, lane = tid & 63, wid = tid >> 6;
    const int lr = lane & 15, hg = lane >> 4;
    const int wg = (blockIdx.x & 7) * 96 + (blockIdx.x >> 3);   // 768/8 = 96
    const int bh = wg >> 4;
    const int b = bh / H_, h = bh - b * H_;
    const int wr0 = (wg & 15) * 128 + wid * 32;
    const hbf* qbh = qg + (size_t)bh * T_ * D_;
    const hbf* kbh = kg + (size_t)bh * T_ * D_;
    const hbf* vbh = vg + (size_t)h * 64 * BT_ + (size_t)b * T_;

    bf16x8 a_q[2][2];
#pragma unroll
    for (int m = 0; m < 2; ++m)
#pragma unroll
        for (int kf = 0; kf < 2; ++kf)
            a_q[m][kf] = *(const bf16x8*)(qbh + (size_t)(wr0 + m * 16 + lr) * D_ + kf * 32 + hg * 8);

    bf16x8 vone;
#pragma unroll
    for (int i = 0; i < 8; ++i) vone[i] = (bf16_t)1.0f;

    f32x4 o[2][4] = {};
    f32x4 lden[2] = {};            // row-sum accumulator, same layout as o
    float mreg[2] = {-3e38f, -3e38f};

    int offK[2], offV[2];
#pragma unroll
    for (int i = 0; i < 2; ++i) {
        int c = tid + i * 256;
        int sw = ((c & 7) ^ ((c >> 3) & 7)) << 4;
        offK[i] = (c >> 3) * 128 + sw;
        offV[i] = (c >> 3) * (BT_ * 2) + sw;
    }
    hbf* sPw = sP + wid * (32 * 64);
    const int sl0 = ((0 * 4 + hg) ^ (lr & 7)) << 4;
    const int sl1 = ((1 * 4 + hg) ^ (lr & 7)) << 4;
    const int bcast = hg * 20;   // source lane hg*16 + (hg*4): for fb[j] add j

    auto stage = [&](int itn, hbf* sKd, hbf* sVd) {
        const char* kp = (const char*)kbh + (size_t)itn * 8192;
        const char* vp = (const char*)vbh + (size_t)itn * 128;
#pragma unroll
        for (int i = 0; i < 2; ++i) {
            load_lds16(kp + offK[i], (char*)sKd + i * 4096 + wid * 1024);
            load_lds16(vp + offV[i], (char*)sVd + i * 4096 + wid * 1024);
        }
    };

    auto tile = [&](const hbf* sKc, const hbf* sVc) {
        f32x4 st[4][2] = {};
        __builtin_amdgcn_s_setprio(1);
#pragma unroll
        for (int kf = 0; kf < 2; ++kf) {
            const int sl = kf ? sl1 : sl0;
#pragma unroll
            for (int n = 0; n < 4; ++n) {
                bf16x8 ak = *(const bf16x8*)((const char*)sKc + (n * 16 + lr) * 128 + sl);
                st[n][0] = __builtin_amdgcn_mfma_f32_16x16x32_bf16(ak, a_q[0][kf], st[n][0], 0, 0, 0);
                st[n][1] = __builtin_amdgcn_mfma_f32_16x16x32_bf16(ak, a_q[1][kf], st[n][1], 0, 0, 0);
            }
        }
        __builtin_amdgcn_s_setprio(0);

#pragma unroll
        for (int m = 0; m < 2; ++m) {
            // balanced max tree (depth 4) over the 16 in-lane values
            float t01, t23, a0, a1;
            f32x4 mx = st[0][m];
            mx[0] = fmaxf(mx[0], st[1][m][0]); mx[1] = fmaxf(mx[1], st[1][m][1]);
            mx[2] = fmaxf(mx[2], st[1][m][2]); mx[3] = fmaxf(mx[3], st[1][m][3]);
            f32x4 my = st[2][m];
            my[0] = fmaxf(my[0], st[3][m][0]); my[1] = fmaxf(my[1], st[3][m][1]);
            my[2] = fmaxf(my[2], st[3][m][2]); my[3] = fmaxf(my[3], st[3][m][3]);
            t01 = fmaxf(fmaxf(mx[0], my[0]), fmaxf(mx[1], my[1]));
            t23 = fmaxf(fmaxf(mx[2], my[2]), fmaxf(mx[3], my[3]));
            float t = fmaxf(t01, t23);
            t = fmaxf(t, __shfl_xor(t, 16, 64));
            t = fmaxf(t, __shfl_xor(t, 32, 64));
            if (__any(t - mreg[m] > 8.0f)) {       // defer-max: rarely taken
                float nm = fmaxf(mreg[m], t);
                float fac = __expf(mreg[m] - nm);
                mreg[m] = nm;
                float fb[4];
#pragma unroll
                for (int j = 0; j < 4; ++j)
                    fb[j] = __shfl(fac, bcast + j, 64);
#pragma unroll
                for (int j = 0; j < 4; ++j) {
                    lden[m][j] *= fb[j];
#pragma unroll
                    for (int nd = 0; nd < 4; ++nd)
                        o[m][nd][j] *= fb[j];
                }
            }
            const int r = m * 16 + lr;
#pragma unroll
            for (int n = 0; n < 4; ++n) {
                float p0 = __expf(st[n][m][0] - mreg[m]);
                float p1 = __expf(st[n][m][1] - mreg[m]);
                float p2 = __expf(st[n][m][2] - mreg[m]);
                float p3 = __expf(st[n][m][3] - mreg[m]);
                bf16x4 w;
                w[0] = (bf16_t)p0; w[1] = (bf16_t)p1; w[2] = (bf16_t)p2; w[3] = (bf16_t)p3;
                *(bf16x4*)((char*)sPw + r * 128 +
                           (((n * 2 + (hg >> 1)) ^ (r & 7)) << 4) + ((hg & 1) * 8)) = w;
            }
        }

        // PV + MFMA row-sum (l = P.1) — P is wave-private, no block barrier
        __builtin_amdgcn_s_setprio(1);
#pragma unroll
        for (int kf = 0; kf < 2; ++kf) {
            const int sl = kf ? sl1 : sl0;
            bf16x8 ap0 = *(const bf16x8*)((const char*)sPw + lr * 128 + sl);
            bf16x8 ap1 = *(const bf16x8*)((const char*)sPw + (16 + lr) * 128 + sl);
            lden[0] = __builtin_amdgcn_mfma_f32_16x16x32_bf16(ap0, vone, lden[0], 0, 0, 0);
            lden[1] = __builtin_amdgcn_mfma_f32_16x16x32_bf16(ap1, vone, lden[1], 0, 0, 0);
#pragma unroll
            for (int nd = 0; nd < 4; ++nd) {
                bf16x8 bv = *(const bf16x8*)((const char*)sVc + (nd * 16 + lr) * 128 + sl);
                o[0][nd] = __builtin_amdgcn_mfma_f32_16x16x32_bf16(ap0, bv, o[0][nd], 0, 0, 0);
                o[1][nd] = __builtin_amdgcn_mfma_f32_16x16x32_bf16(ap1, bv, o[1][nd], 0, 0, 0);
            }
        }
        __builtin_amdgcn_s_setprio(0);
    };

    const int NT = T_ / 64;   // 32, even
    stage(0, sK0, sV0);
    __syncthreads();
    for (int it = 0; it < NT; it += 2) {
        stage(it + 1, sK1, sV1);
        tile(sK0, sV0);
        __syncthreads();
        if (it + 2 < NT) stage(it + 2, sK0, sV0);
        tile(sK1, sV1);
        __syncthreads();
    }

    // epilogue: l already in o's layout — direct divide, no broadcast
#pragma unroll
    for (int m = 0; m < 2; ++m) {
        f32x4 rinv;
#pragma unroll
        for (int j = 0; j < 4; ++j) rinv[j] = 1.0f / lden[m][j];
#pragma unroll
        for (int nd = 0; nd < 4; ++nd)
#pragma unroll
            for (int j = 0; j < 4; ++j) {
                int row = wr0 + m * 16 + hg * 4 + j;
                int col = nd * 16 + lr;
                outA[((size_t)(b * T_ + row)) * C_ + h * D_ + col] =
                    __float2bfloat16(o[m][nd][j] * rinv[j]);
            }
    }
}

// ---------------- launch ----------------
extern "C" void kernel_launch(void* const* d_in, const int* in_sizes, int n_in,
                              void* d_out, int out_size, void* d_ws, size_t ws_size,
                              hipStream_t stream)
{
    const float* x    = (const float*)d_in[0];
    const float* Wq   = (const float*)d_in[1];
    const float* Wk   = (const float*)d_in[2];
    const float* Wv   = (const float*)d_in[3];
    const float* Wo   = (const float*)d_in[4];
    const float* bo   = (const float*)d_in[5];
    const float* ln1g = (const float*)d_in[6];
    const float* ln1b = (const float*)d_in[7];
    const float* ln2g = (const float*)d_in[8];
    const float* ln2b = (const float*)d_in[9];
    const float* W1   = (const float*)d_in[10];
    const float* b1   = (const float*)d_in[11];
    const float* W2   = (const float*)d_in[12];
    const float* b2   = (const float*)d_in[13];
    float* out = (float*)d_out;
    char* ws = (char*)d_ws;

    hbf*  xn    = (hbf*)(ws + 0);            // 12.58 MB
    hbf*  WqkT  = (hbf*)(ws + 12582912);     // [2304][768] 3.54 MB (q,k,v rows)
    hbf*  qb    = (hbf*)(ws + 16121856);     // 12.58 MB
    hbf*  kb    = (hbf*)(ws + 28704768);     // 12.58 MB
    hbf*  vT    = (hbf*)(ws + 41287680);     // [768][8192] 12.58 MB
    hbf*  h1    = (hbf*)(ws + 0);            // 50.33 MB overlay (dead inputs by MLP)
    hbf*  attnB = (hbf*)(ws + 53870592);     // 12.58 MB
    hbf*  yln   = (hbf*)(ws + 53870592);     // overlays attnB
    hbf*  x2b   = (hbf*)(ws + 66453504);     // 12.58 MB (bf16 residual-1)
    hbf*  WoT   = (hbf*)(ws + 91619328);     // 1.18 MB
    hbf*  W1T   = (hbf*)(ws + 92798976);     // 4.72 MB
    hbf*  W2T   = (hbf*)(ws + 97517568);     // 4.72 MB (end 102,236,160)

    const float SCALE = 0.036084391824351615f;  // 768^-0.5

    pack_qkv3<<<dim3(1, 12, 36), 256, 0, stream>>>(Wq, Wk, Wv, WqkT);
    transpose_pack<<<dim3(12, 12, 1), 256, 0, stream>>>(Wo, WoT, 768, 768);
    transpose_pack<<<dim3(48, 12, 1), 256, 0, stream>>>(W1, W1T, 768, 3072);
    transpose_pack<<<dim3(12, 48, 1), 256, 0, stream>>>(W2, W2T, 3072, 768);
    ln_kernel<float><<<8192, 256, 0, stream>>>(x, ln1g, ln1b, xn);
    gemm_kernel<3,128><<<1152, 256, 0, stream>>>(xn, WqkT, nullptr, nullptr, nullptr, nullptr,
        nullptr, 8192, 2304, 768, qb, kb, vT, SCALE, 18);
    attn_kernel<<<768, 256, 0, stream>>>(qb, kb, vT, attnB);
    gemm_kernel<4,64><<<768, 256, 0, stream>>>(attnB, WoT, nullptr, x2b, bo, x,
        nullptr, 8192, 768, 768, nullptr, nullptr, nullptr, 1.0f, 12);
    ln_kernel<hbf><<<8192, 256, 0, stream>>>(x2b, ln2g, ln2b, yln);
    gemm_kernel<2,128><<<1536, 256, 0, stream>>>(yln, W1T, nullptr, h1, b1, nullptr,
        nullptr, 8192, 3072, 768, nullptr, nullptr, nullptr, 1.0f, 24);
    gemm_kernel<5,64><<<768, 256, 0, stream>>>(h1, W2T, out, nullptr, b2, nullptr,
        x2b, 8192, 768, 3072, nullptr, nullptr, nullptr, 1.0f, 12);
}